// Round 10
// baseline (161.838 us; speedup 1.0000x reference)
//
#include <hip/hip_runtime.h>

#define N_NODES 50000
#define NPAD    50048   // 391 * 128
#define FEAT    128
#define NZ      64
#define E_EDGES 800000
#define BN_EPS  1e-5f
#define SLOPE   0.2f
#define NB      196     // ceil(50048 / 256)
#define NBUK    391     // buckets of 128 dst nodes
#define NCHK    128     // edge chunks
#define CE      6250    // edges per chunk
#define XCONV_B 4688    // ceil(N*24/256)

typedef __attribute__((ext_vector_type(8))) short short8v;
typedef __attribute__((ext_vector_type(4))) float f32x4;

__device__ __forceinline__ unsigned short f2bf(float v) {
  union { float f; unsigned u; } c; c.f = v;
  unsigned r = c.u + 0x7FFFu + ((c.u >> 16) & 1u);
  return (unsigned short)(r >> 16);
}
__device__ __forceinline__ float bflo32(unsigned u) {
  union { unsigned x; float f; } c; c.x = u << 16; return c.f;
}
__device__ __forceinline__ float bfhi32(unsigned u) {
  union { unsigned x; float f; } c; c.x = u & 0xFFFF0000u; return c.f;
}
__device__ __forceinline__ void gload16(const void* src, const void* lds) {
  __builtin_amdgcn_global_load_lds(
      (const __attribute__((address_space(1))) unsigned int*)src,
      (__attribute__((address_space(3))) unsigned int*)lds, 16, 0, 0);
}
__device__ __forceinline__ float lrelu(float v) {
  return (v >= 0.f) ? v : SLOPE * v;
}

// ---------------------------------------------------------------------------
// Prep: wconv (blocks [0,592)) + xconv ([592, 592+4688)) + hist (last 128).
// ---------------------------------------------------------------------------
__global__ __launch_bounds__(256) void prep_kernel(
    const float* __restrict__ nf, const float* __restrict__ noise,
    const int* __restrict__ ei,
    const float* __restrict__ Wl, const float* __restrict__ Wr,
    const float* __restrict__ W1, const float* __restrict__ W2,
    const float* __restrict__ W3, const float* __restrict__ W4,
    unsigned short* __restrict__ xa,
    unsigned short* __restrict__ Wc_, unsigned short* __restrict__ W1_,
    unsigned short* __restrict__ W2_, unsigned short* __restrict__ W3_,
    unsigned short* __restrict__ W4_, int* __restrict__ cnt) {
  __shared__ int h[NBUK];
  int b = blockIdx.x, t = threadIdx.x;
  if (b < 592) {
    int idx = b * 256 + t;
    if (idx < 49152) {
      int k = idx % 192, m = idx / 192;
      Wc_[(size_t)m * 384 + k] = f2bf(Wl[(size_t)k * 256 + m]);
    } else if (idx < 98304) {
      int local = idx - 49152;
      int k = local % 192, m = local / 192;
      Wc_[(size_t)m * 384 + 192 + k] = f2bf(Wr[(size_t)k * 256 + m]);
    } else if (idx < 131072) {
      int local = idx - 98304;
      int k = local % 256, m = local / 256;
      W1_[(size_t)m * 256 + k] = f2bf(W1[(size_t)k * 128 + m]);
    } else if (idx < 139264) {
      int local = idx - 131072;
      int k = local % 128, m = local / 128;
      W2_[(size_t)m * 128 + k] = f2bf(W2[(size_t)k * 64 + m]);
    } else if (idx < 143360) {
      int local = idx - 139264;
      int k = local % 64, m = local / 64;
      W3_[(size_t)m * 64 + k] = f2bf(W3[(size_t)k * 64 + m]);
    } else if (idx < 151552) {
      int local = idx - 143360;
      int k = local % 64, m = local / 64;
      W4_[(size_t)m * 64 + k] = f2bf(W4[(size_t)k * 128 + m]);
    }
  } else if (b < 592 + XCONV_B) {
    int i = (b - 592) * 256 + t;
    if (i < N_NODES * 24) {
      int n = i / 24, s = i % 24;
      float4 va, vb;
      if (s < 16) {
        va = ((const float4*)nf)[(size_t)n * 32 + s * 2];
        vb = ((const float4*)nf)[(size_t)n * 32 + s * 2 + 1];
      } else {
        int u = s - 16;
        va = ((const float4*)noise)[(size_t)n * 16 + u * 2];
        vb = ((const float4*)noise)[(size_t)n * 16 + u * 2 + 1];
      }
      unsigned p0 = (unsigned)f2bf(va.x) | ((unsigned)f2bf(va.y) << 16);
      unsigned p1 = (unsigned)f2bf(va.z) | ((unsigned)f2bf(va.w) << 16);
      unsigned p2 = (unsigned)f2bf(vb.x) | ((unsigned)f2bf(vb.y) << 16);
      unsigned p3 = (unsigned)f2bf(vb.z) | ((unsigned)f2bf(vb.w) << 16);
      *(uint4*)&xa[(size_t)n * 384 + 192 + s * 8] = make_uint4(p0, p1, p2, p3);
    }
  } else {
    int c = b - (592 + XCONV_B);
    for (int i = t; i < NBUK; i += 256) h[i] = 0;
    __syncthreads();
    int e0 = c * CE;
    for (int e = e0 + t; e < e0 + CE; e += 256)
      atomicAdd(&h[ei[E_EDGES + e] >> 7], 1);
    __syncthreads();
    for (int i = t; i < NBUK; i += 256) cnt[i * NCHK + c] = h[i];
  }
}

// ---------------------------------------------------------------------------
// Scan chain.
// ---------------------------------------------------------------------------
template <int LEN>
__global__ __launch_bounds__(256) void block_sum_kernel(
    const int* __restrict__ in, int* __restrict__ bsum) {
  __shared__ int sh[256];
  int i = blockIdx.x * 256 + threadIdx.x;
  sh[threadIdx.x] = (i < LEN) ? in[i] : 0;
  __syncthreads();
  for (int s = 128; s > 0; s >>= 1) {
    if (threadIdx.x < s) sh[threadIdx.x] += sh[threadIdx.x + s];
    __syncthreads();
  }
  if (threadIdx.x == 0) bsum[blockIdx.x] = sh[0];
}

__global__ __launch_bounds__(256) void scan_bsum_kernel(int* __restrict__ bsum) {
  __shared__ int sh[256];
  int t = threadIdx.x;
  sh[t] = (t < NB) ? bsum[t] : 0;
  __syncthreads();
  for (int off = 1; off < 256; off <<= 1) {
    int v = (t >= off) ? sh[t - off] : 0;
    __syncthreads();
    sh[t] += v;
    __syncthreads();
  }
  if (t < NB) bsum[t] = (t == 0) ? 0 : sh[t - 1];
}

template <int LEN>
__global__ __launch_bounds__(256) void scan_chunk_kernel(
    const int* __restrict__ in, const int* __restrict__ bsum,
    int* __restrict__ out) {
  __shared__ int sh[256];
  int t = threadIdx.x;
  int i = blockIdx.x * 256 + t;
  int v = (i < LEN) ? in[i] : 0;
  sh[t] = v;
  __syncthreads();
  for (int off = 1; off < 256; off <<= 1) {
    int u = (t >= off) ? sh[t - off] : 0;
    __syncthreads();
    sh[t] += u;
    __syncthreads();
  }
  if (i < LEN) out[i] = bsum[blockIdx.x] + sh[t] - v;
}

__global__ __launch_bounds__(256) void scatter_kernel(
    const int* __restrict__ ei, const int* __restrict__ ebase,
    unsigned* __restrict__ ebuf) {
  __shared__ int cur[NBUK];
  int c = blockIdx.x, t = threadIdx.x;
  for (int i = t; i < NBUK; i += 256) cur[i] = ebase[i * NCHK + c];
  __syncthreads();
  int e0 = c * CE;
  for (int e = e0 + t; e < e0 + CE; e += 256) {
    int s = ei[e], d = ei[E_EDGES + e];
    int p = atomicAdd(&cur[d >> 7], 1);
    ebuf[p] = ((unsigned)(d & 127) << 16) | (unsigned)s;
  }
}

__global__ __launch_bounds__(256) void sortb_kernel(
    const unsigned* __restrict__ ebuf, const int* __restrict__ ebase,
    int* __restrict__ csr, int* __restrict__ deg, int* __restrict__ cursor) {
  __shared__ int h[128], sc[128], curn[128];
  int b = blockIdx.x, t = threadIdx.x;
  int beg = ebase[b * NCHK];
  int endb = (b == NBUK - 1) ? E_EDGES : ebase[(b + 1) * NCHK];
  if (t < 128) h[t] = 0;
  __syncthreads();
  for (int i = beg + t; i < endb; i += 256) atomicAdd(&h[ebuf[i] >> 16], 1);
  __syncthreads();
  if (t < 128) sc[t] = h[t];
  __syncthreads();
  for (int off = 1; off < 128; off <<= 1) {
    int v = (t >= off && t < 128) ? sc[t - off] : 0;
    __syncthreads();
    if (t < 128) sc[t] += v;
    __syncthreads();
  }
  if (t < 128) {
    curn[t] = sc[t] - h[t];
    int n = b * 128 + t;
    if (n < N_NODES) {
      deg[n] = h[t];
      cursor[n] = beg + sc[t];
    }
  }
  __syncthreads();
  for (int i = beg + t; i < endb; i += 256) {
    unsigned u = ebuf[i];
    int p = atomicAdd(&curn[u >> 16], 1);
    csr[beg + p] = (int)(u & 0xFFFFu) * 768 + 384;  // byte offset of x-part
  }
}

// ---------------------------------------------------------------------------
// Gather (request-rate bound at ~6.3 TB/s effective; unchanged).
// ---------------------------------------------------------------------------
__global__ __launch_bounds__(256) void gather_kernel(
    const int* __restrict__ csr, const int* __restrict__ cursor,
    const int* __restrict__ deg, unsigned short* __restrict__ xa) {
  int wid = (blockIdx.x * blockDim.x + threadIdx.x) >> 6;
  int lane = threadIdx.x & 63;
  if (wid >= N_NODES) return;
  int d = deg[wid];
  int end = cursor[wid];
  int start = end - d;
  const bool act = lane < 48;
  const char* base = (const char*)xa + (size_t)(lane * 8);

  float a0 = 0.f, a1 = 0.f, a2 = 0.f, a3 = 0.f;
  float b0 = 0.f, b1 = 0.f, b2 = 0.f, b3 = 0.f;
  int j = start;
  for (; j + 7 < end; j += 8) {
    int o0 = csr[j],     o1 = csr[j + 1], o2 = csr[j + 2], o3 = csr[j + 3];
    int o4 = csr[j + 4], o5 = csr[j + 5], o6 = csr[j + 6], o7 = csr[j + 7];
    if (act) {
      uint2 v0 = *(const uint2*)(base + o0);
      uint2 v1 = *(const uint2*)(base + o1);
      uint2 v2 = *(const uint2*)(base + o2);
      uint2 v3 = *(const uint2*)(base + o3);
      uint2 v4 = *(const uint2*)(base + o4);
      uint2 v5 = *(const uint2*)(base + o5);
      uint2 v6 = *(const uint2*)(base + o6);
      uint2 v7 = *(const uint2*)(base + o7);
      a0 += bflo32(v0.x) + bflo32(v2.x) + bflo32(v4.x) + bflo32(v6.x);
      a1 += bfhi32(v0.x) + bfhi32(v2.x) + bfhi32(v4.x) + bfhi32(v6.x);
      a2 += bflo32(v0.y) + bflo32(v2.y) + bflo32(v4.y) + bflo32(v6.y);
      a3 += bfhi32(v0.y) + bfhi32(v2.y) + bfhi32(v4.y) + bfhi32(v6.y);
      b0 += bflo32(v1.x) + bflo32(v3.x) + bflo32(v5.x) + bflo32(v7.x);
      b1 += bfhi32(v1.x) + bfhi32(v3.x) + bfhi32(v5.x) + bfhi32(v7.x);
      b2 += bflo32(v1.y) + bflo32(v3.y) + bflo32(v5.y) + bflo32(v7.y);
      b3 += bfhi32(v1.y) + bfhi32(v3.y) + bfhi32(v5.y) + bfhi32(v7.y);
    }
  }
  for (; j < end; ++j) {
    int o = csr[j];
    if (act) {
      uint2 v = *(const uint2*)(base + o);
      a0 += bflo32(v.x); a1 += bfhi32(v.x);
      a2 += bflo32(v.y); a3 += bfhi32(v.y);
    }
  }
  if (act) {
    float inv = 1.0f / fmaxf((float)d, 1.0f);
    float m0 = (a0 + b0) * inv, m1 = (a1 + b1) * inv;
    float m2 = (a2 + b2) * inv, m3 = (a3 + b3) * inv;
    unsigned r0 = (unsigned)f2bf(m0) | ((unsigned)f2bf(m1) << 16);
    unsigned r1 = (unsigned)f2bf(m2) | ((unsigned)f2bf(m3) << 16);
    *(uint2*)&xa[(size_t)wid * 384 + (size_t)lane * 4] = make_uint2(r0, r1);
  }
}

// ---------------------------------------------------------------------------
// Fully fused network: combine(K=384, 256 out) -> fc1 -> fc2 -> fc3 -> fc4.
// 391 blocks x 256 thr (4 waves, 2x2), 80 KB LDS, 2 blocks/CU.
// LDS map (ushort): X=[0,32768): combine sA[0,8192)+sB[8192,24576);
//   then h = two [128][128] halves at [0,16384)/[16384,32768);
//   then h1 [128][128] @0, h2 [128][64] @16384, h3 [128][64] @24576.
// Y=[32768,40960): 16 KB weight-staging window.
// Swizzles: C=64 rows: slot^(row&7); C=128 rows: slot^((row&7)<<1).
// FIX vs r9: W1 staging loops were j<2 (half the 128x64 tile); now j<4.
// ---------------------------------------------------------------------------
__global__ __launch_bounds__(256) void gemm_chain(
    const unsigned short* __restrict__ xa, const unsigned short* __restrict__ Wc_,
    const unsigned short* __restrict__ W1_, const unsigned short* __restrict__ W2_,
    const unsigned short* __restrict__ W3_, const unsigned short* __restrict__ W4_,
    const float* __restrict__ bl, const float* __restrict__ gam,
    const float* __restrict__ bet, const float* __restrict__ bmean,
    const float* __restrict__ bvar, const float* __restrict__ b1,
    const float* __restrict__ b2, const float* __restrict__ b3,
    const float* __restrict__ b4, float* __restrict__ outp) {
  __shared__ unsigned short lds[40960];
  unsigned short* X = lds;
  unsigned short* Y = lds + 32768;

  const int tid = threadIdx.x;
  const int wid = tid >> 6;
  const int lane = tid & 63;
  const int g = lane >> 4;
  const int rowbase = blockIdx.x * 128;
  const int wr = wid >> 1, wc = wid & 1;
  const int slog = (lane & 7) ^ (lane >> 3);  // C=64 staging xor

  // ================= combine: acc[4][8], K=384 =================
  f32x4 acc[4][8];
#pragma unroll
  for (int i = 0; i < 4; ++i)
#pragma unroll
    for (int j = 0; j < 8; ++j) acc[i][j] = (f32x4)0.f;

  for (int kt = 0; kt < 6; ++kt) {
    const int kb = kt * 64;
    __syncthreads();
#pragma unroll
    for (int j = 0; j < 8; ++j) {  // sB: Wc 256 rows (32 ops)
      int o = j * 4 + wid;
      int row = o * 8 + (lane >> 3);
      gload16((const char*)Wc_ + ((size_t)row * 384 + kb) * 2 + (size_t)slog * 16,
              X + 8192 + o * 512);
    }
#pragma unroll
    for (int j = 0; j < 4; ++j) {  // sA: xa 128 rows (16 ops)
      int o = j * 4 + wid;
      int row = o * 8 + (lane >> 3);
      gload16((const char*)xa + ((size_t)(rowbase + row) * 384 + kb) * 2 +
                  (size_t)slog * 16,
              X + o * 512);
    }
    __syncthreads();

#pragma unroll
    for (int kk = 0; kk < 2; ++kk) {
      short8v a[4];
#pragma unroll
      for (int fi = 0; fi < 4; ++fi) {
        int rt = wr * 64 + fi * 16 + (lane & 15);
        int sl = (kk * 4 + g) ^ (rt & 7);
        a[fi] = *(const short8v*)&X[rt * 64 + sl * 8];
      }
#pragma unroll
      for (int fjh = 0; fjh < 2; ++fjh) {
        short8v b[4];
#pragma unroll
        for (int q = 0; q < 4; ++q) {
          int ct = wc * 128 + (fjh * 4 + q) * 16 + (lane & 15);
          int sl = (kk * 4 + g) ^ (ct & 7);
          b[q] = *(const short8v*)&X[8192 + ct * 64 + sl * 8];
        }
#pragma unroll
        for (int fi = 0; fi < 4; ++fi)
#pragma unroll
          for (int q = 0; q < 4; ++q)
            acc[fi][fjh * 4 + q] = __builtin_amdgcn_mfma_f32_16x16x32_bf16(
                a[fi], b[q], acc[fi][fjh * 4 + q], 0, 0, 0);
      }
    }
  }

  // ---- h epilogue (BN+lrelu) -> two [128][128] LDS halves; stage W1 step0 ----
  __syncthreads();
#pragma unroll
  for (int fj = 0; fj < 8; ++fj) {
    int gc = wc * 128 + fj * 16 + (lane & 15);
    float s = gam[gc] * rsqrtf(bvar[gc] + BN_EPS);
    float sh = bl[gc] * s + bet[gc] - bmean[gc] * s;
    int lc = gc & 127;
#pragma unroll
    for (int fi = 0; fi < 4; ++fi)
#pragma unroll
      for (int r = 0; r < 4; ++r) {
        int rt = wr * 64 + fi * 16 + (g << 2) + r;
        float v = lrelu(acc[fi][fj][r] * s + sh);
        X[wc * 16384 + rt * 128 + (((lc >> 3) ^ ((rt & 7) << 1)) << 3) +
          (lc & 7)] = f2bf(v);
      }
  }
#pragma unroll
  for (int j = 0; j < 4; ++j) {  // W1 step 0: 128 cols x 64 k = 16 ops (FIX)
    int o = j * 4 + wid;
    int col = o * 8 + (lane >> 3);
    gload16((const char*)W1_ + ((size_t)col * 256) * 2 + (size_t)slog * 16,
            Y + o * 512);
  }
  __syncthreads();

  // ================= fc1: K=256, out 128 =================
  f32x4 acc1[4][4];
#pragma unroll
  for (int i = 0; i < 4; ++i)
#pragma unroll
    for (int j = 0; j < 4; ++j) acc1[i][j] = (f32x4)0.f;

  for (int kt = 0; kt < 4; ++kt) {
    if (kt) {
      __syncthreads();
#pragma unroll
      for (int j = 0; j < 4; ++j) {  // 16 ops (FIX)
        int o = j * 4 + wid;
        int col = o * 8 + (lane >> 3);
        gload16((const char*)W1_ + ((size_t)col * 256 + kt * 64) * 2 +
                    (size_t)slog * 16,
                Y + o * 512);
      }
      __syncthreads();
    }
    const int half = kt >> 1;
    const int lkb8 = (kt & 1) * 8;
#pragma unroll
    for (int kk = 0; kk < 2; ++kk) {
      short8v a[4], b[4];
#pragma unroll
      for (int fi = 0; fi < 4; ++fi) {
        int rt = wr * 64 + fi * 16 + (lane & 15);
        int ph = (lkb8 + kk * 4 + g) ^ ((rt & 7) << 1);
        a[fi] = *(const short8v*)&X[half * 16384 + rt * 128 + ph * 8];
      }
#pragma unroll
      for (int fj = 0; fj < 4; ++fj) {
        int ct = wc * 64 + fj * 16 + (lane & 15);
        int sl = (kk * 4 + g) ^ (ct & 7);
        b[fj] = *(const short8v*)&Y[ct * 64 + sl * 8];
      }
#pragma unroll
      for (int fi = 0; fi < 4; ++fi)
#pragma unroll
        for (int fj = 0; fj < 4; ++fj)
          acc1[fi][fj] = __builtin_amdgcn_mfma_f32_16x16x32_bf16(
              a[fi], b[fj], acc1[fi][fj], 0, 0, 0);
    }
  }

  // ---- h1 -> X[0,16384) [128][128]; stage W2 (64x128, 16 ops) ----
  __syncthreads();
#pragma unroll
  for (int fj = 0; fj < 4; ++fj) {
    int gc = wc * 64 + fj * 16 + (lane & 15);
    float bb = b1[gc];
#pragma unroll
    for (int fi = 0; fi < 4; ++fi)
#pragma unroll
      for (int r = 0; r < 4; ++r) {
        int rt = wr * 64 + fi * 16 + (g << 2) + r;
        float v = lrelu(acc1[fi][fj][r] + bb);
        X[rt * 128 + (((gc >> 3) ^ ((rt & 7) << 1)) << 3) + (gc & 7)] = f2bf(v);
      }
  }
#pragma unroll
  for (int j = 0; j < 4; ++j) {  // W2: [64][128], C=128 staging
    int o = j * 4 + wid;
    int rloc = o * 4 + (lane >> 4);
    int sl4 = (lane & 15) ^ ((rloc & 7) << 1);
    gload16((const char*)W2_ + ((size_t)rloc * 128) * 2 + (size_t)sl4 * 16,
            Y + o * 512);
  }
  __syncthreads();

  // ================= fc2: K=128, out 64 =================
  f32x4 acc2[4][2];
#pragma unroll
  for (int i = 0; i < 4; ++i) { acc2[i][0] = (f32x4)0.f; acc2[i][1] = (f32x4)0.f; }
#pragma unroll
  for (int kk = 0; kk < 4; ++kk) {
    short8v a[4], b[2];
#pragma unroll
    for (int fi = 0; fi < 4; ++fi) {
      int rt = wr * 64 + fi * 16 + (lane & 15);
      int ph = (kk * 4 + g) ^ ((rt & 7) << 1);
      a[fi] = *(const short8v*)&X[rt * 128 + ph * 8];
    }
#pragma unroll
    for (int fj = 0; fj < 2; ++fj) {
      int ct = wc * 32 + fj * 16 + (lane & 15);
      int ph = (kk * 4 + g) ^ ((ct & 7) << 1);
      b[fj] = *(const short8v*)&Y[ct * 128 + ph * 8];
    }
#pragma unroll
    for (int fi = 0; fi < 4; ++fi)
#pragma unroll
      for (int fj = 0; fj < 2; ++fj)
        acc2[fi][fj] = __builtin_amdgcn_mfma_f32_16x16x32_bf16(
            a[fi], b[fj], acc2[fi][fj], 0, 0, 0);
  }

  // ---- h2 -> X[16384,24576) [128][64]; stage W3 (64x64, 8 ops) ----
  __syncthreads();
#pragma unroll
  for (int fj = 0; fj < 2; ++fj) {
    int gc = wc * 32 + fj * 16 + (lane & 15);
    float bb = b2[gc];
#pragma unroll
    for (int fi = 0; fi < 4; ++fi)
#pragma unroll
      for (int r = 0; r < 4; ++r) {
        int rt = wr * 64 + fi * 16 + (g << 2) + r;
        float v = lrelu(acc2[fi][fj][r] + bb);
        X[16384 + rt * 64 + (((gc >> 3) ^ (rt & 7)) << 3) + (gc & 7)] = f2bf(v);
      }
  }
#pragma unroll
  for (int j = 0; j < 2; ++j) {  // W3: [64][64]
    int o = j * 4 + wid;
    int rloc = o * 8 + (lane >> 3);
    gload16((const char*)W3_ + ((size_t)rloc * 64) * 2 + (size_t)slog * 16,
            Y + o * 512);
  }
  __syncthreads();

  // ================= fc3: K=64, out 64 =================
  f32x4 acc3[4][2];
#pragma unroll
  for (int i = 0; i < 4; ++i) { acc3[i][0] = (f32x4)0.f; acc3[i][1] = (f32x4)0.f; }
#pragma unroll
  for (int kk = 0; kk < 2; ++kk) {
    short8v a[4], b[2];
#pragma unroll
    for (int fi = 0; fi < 4; ++fi) {
      int rt = wr * 64 + fi * 16 + (lane & 15);
      int sl = (kk * 4 + g) ^ (rt & 7);
      a[fi] = *(const short8v*)&X[16384 + rt * 64 + sl * 8];
    }
#pragma unroll
    for (int fj = 0; fj < 2; ++fj) {
      int ct = wc * 32 + fj * 16 + (lane & 15);
      int sl = (kk * 4 + g) ^ (ct & 7);
      b[fj] = *(const short8v*)&Y[ct * 64 + sl * 8];
    }
#pragma unroll
    for (int fi = 0; fi < 4; ++fi)
#pragma unroll
      for (int fj = 0; fj < 2; ++fj)
        acc3[fi][fj] = __builtin_amdgcn_mfma_f32_16x16x32_bf16(
            a[fi], b[fj], acc3[fi][fj], 0, 0, 0);
  }

  // ---- h3 -> X[24576,32768) [128][64]; stage W4 (128x64, 16 ops) ----
  __syncthreads();
#pragma unroll
  for (int fj = 0; fj < 2; ++fj) {
    int gc = wc * 32 + fj * 16 + (lane & 15);
    float bb = b3[gc];
#pragma unroll
    for (int fi = 0; fi < 4; ++fi)
#pragma unroll
      for (int r = 0; r < 4; ++r) {
        int rt = wr * 64 + fi * 16 + (g << 2) + r;
        float v = lrelu(acc3[fi][fj][r] + bb);
        X[24576 + rt * 64 + (((gc >> 3) ^ (rt & 7)) << 3) + (gc & 7)] = f2bf(v);
      }
  }
#pragma unroll
  for (int j = 0; j < 4; ++j) {  // W4: [128][64]
    int o = j * 4 + wid;
    int rloc = o * 8 + (lane >> 3);
    gload16((const char*)W4_ + ((size_t)rloc * 64) * 2 + (size_t)slog * 16,
            Y + o * 512);
  }
  __syncthreads();

  // ================= fc4: K=64, out 128, f32 global =================
  f32x4 acc4[4][4];
#pragma unroll
  for (int i = 0; i < 4; ++i)
#pragma unroll
    for (int j = 0; j < 4; ++j) acc4[i][j] = (f32x4)0.f;
#pragma unroll
  for (int kk = 0; kk < 2; ++kk) {
    short8v a[4], b[4];
#pragma unroll
    for (int fi = 0; fi < 4; ++fi) {
      int rt = wr * 64 + fi * 16 + (lane & 15);
      int sl = (kk * 4 + g) ^ (rt & 7);
      a[fi] = *(const short8v*)&X[24576 + rt * 64 + sl * 8];
    }
#pragma unroll
    for (int fj = 0; fj < 4; ++fj) {
      int ct = wc * 64 + fj * 16 + (lane & 15);
      int sl = (kk * 4 + g) ^ (ct & 7);
      b[fj] = *(const short8v*)&Y[ct * 64 + sl * 8];
    }
#pragma unroll
    for (int fi = 0; fi < 4; ++fi)
#pragma unroll
      for (int fj = 0; fj < 4; ++fj)
        acc4[fi][fj] = __builtin_amdgcn_mfma_f32_16x16x32_bf16(
            a[fi], b[fj], acc4[fi][fj], 0, 0, 0);
  }

  const int crow0 = rowbase + wr * 64;
#pragma unroll
  for (int fj = 0; fj < 4; ++fj) {
    int gc = wc * 64 + fj * 16 + (lane & 15);
    float bb = b4[gc];
#pragma unroll
    for (int fi = 0; fi < 4; ++fi)
#pragma unroll
      for (int r = 0; r < 4; ++r) {
        int gr = crow0 + fi * 16 + (g << 2) + r;
        if (gr < N_NODES) {
          float v = lrelu(acc4[fi][fj][r] + bb);
          outp[(size_t)gr * FEAT + gc] = v;
        }
      }
  }
}

extern "C" void kernel_launch(void* const* d_in, const int* in_sizes, int n_in,
                              void* d_out, int out_size, void* d_ws, size_t ws_size,
                              hipStream_t stream) {
  const float* nf    = (const float*)d_in[0];
  const float* noise = (const float*)d_in[1];
  const int*   ei    = (const int*)d_in[2];
  const float* Wl    = (const float*)d_in[4];
  const float* bl    = (const float*)d_in[5];
  const float* Wr    = (const float*)d_in[6];
  const float* gam   = (const float*)d_in[7];
  const float* bet   = (const float*)d_in[8];
  const float* bmean = (const float*)d_in[9];
  const float* bvar  = (const float*)d_in[10];
  const float* fc1w  = (const float*)d_in[11];
  const float* fc1b  = (const float*)d_in[12];
  const float* fc2w  = (const float*)d_in[13];
  const float* fc2b  = (const float*)d_in[14];
  const float* fc3w  = (const float*)d_in[15];
  const float* fc3b  = (const float*)d_in[16];
  const float* fc4w  = (const float*)d_in[17];
  const float* fc4b  = (const float*)d_in[18];
  float* outp = (float*)d_out;

  // ---- workspace (ushort units unless noted) ----
  unsigned short* xa  = (unsigned short*)d_ws;             // [NPAD][384]: [agg|x]
  unsigned short* Wc_ = xa + (size_t)NPAD * 384;           // 256*384
  unsigned short* W1_ = Wc_ + 256 * 384;                   // 128*256
  unsigned short* W2_ = W1_ + 128 * 256;                   // 64*128
  unsigned short* W3_ = W2_ + 64 * 128;                    // 64*64
  unsigned short* W4_ = W3_ + 64 * 64;                     // 128*64
  int* deg    = (int*)(W4_ + 128 * 64);                    // N
  int* cursor = deg + N_NODES;                             // N
  int* bsum   = cursor + N_NODES;                          // 256
  int* cnt    = bsum + 256;                                // NBUK*NCHK
  int* ebase  = cnt + NBUK * NCHK;                         // NBUK*NCHK
  int*      csr  = (int*)d_out;                            // E ints (scratch)
  unsigned* ebuf = (unsigned*)d_out + E_EDGES;             // E uints (scratch)

  // --- prep: wconv + xconv + hist in one launch ---
  prep_kernel<<<592 + XCONV_B + NCHK, 256, 0, stream>>>(
      nf, noise, ei, Wl, Wr, fc1w, fc2w, fc3w, fc4w,
      xa, Wc_, W1_, W2_, W3_, W4_, cnt);

  // --- scan + scatter + per-bucket sort ---
  block_sum_kernel<NBUK * NCHK><<<NB, 256, 0, stream>>>(cnt, bsum);
  scan_bsum_kernel<<<1, 256, 0, stream>>>(bsum);
  scan_chunk_kernel<NBUK * NCHK><<<NB, 256, 0, stream>>>(cnt, bsum, ebase);
  scatter_kernel<<<NCHK, 256, 0, stream>>>(ei, ebase, ebuf);
  sortb_kernel<<<NBUK, 256, 0, stream>>>(ebuf, ebase, csr, deg, cursor);

  // --- aggregate ---
  gather_kernel<<<(N_NODES + 3) / 4, 256, 0, stream>>>(csr, cursor, deg, xa);

  // --- fully fused network ---
  gemm_chain<<<NPAD / 128, 256, 0, stream>>>(
      xa, Wc_, W1_, W2_, W3_, W4_,
      bl, gam, bet, bmean, bvar, fc1b, fc2b, fc3b, fc4b, outp);
}

// Round 11
// 145.999 us; speedup vs baseline: 1.1085x; 1.1085x over previous
//
#include <hip/hip_runtime.h>

#define N_NODES 50000
#define NPAD    50048   // 391 * 128
#define FEAT    128
#define NZ      64
#define E_EDGES 800000
#define BN_EPS  1e-5f
#define SLOPE   0.2f
#define NB      196     // ceil(50048 / 256)
#define NBUK    391     // buckets of 128 dst nodes
#define NCHK    128     // edge chunks
#define CE      6250    // edges per chunk
#define XCONV_B 4688    // ceil(N*24/256)

typedef __attribute__((ext_vector_type(8))) short short8v;
typedef __attribute__((ext_vector_type(4))) float f32x4;

__device__ __forceinline__ unsigned short f2bf(float v) {
  union { float f; unsigned u; } c; c.f = v;
  unsigned r = c.u + 0x7FFFu + ((c.u >> 16) & 1u);
  return (unsigned short)(r >> 16);
}
__device__ __forceinline__ float bflo32(unsigned u) {
  union { unsigned x; float f; } c; c.x = u << 16; return c.f;
}
__device__ __forceinline__ float bfhi32(unsigned u) {
  union { unsigned x; float f; } c; c.x = u & 0xFFFF0000u; return c.f;
}
__device__ __forceinline__ void gload16(const void* src, const void* lds) {
  __builtin_amdgcn_global_load_lds(
      (const __attribute__((address_space(1))) unsigned int*)src,
      (__attribute__((address_space(3))) unsigned int*)lds, 16, 0, 0);
}

// ---------------------------------------------------------------------------
// Prep: wconv (blocks [0,592)) + xconv ([592, 592+4688)) + hist (last 128).
// ---------------------------------------------------------------------------
__global__ __launch_bounds__(256) void prep_kernel(
    const float* __restrict__ nf, const float* __restrict__ noise,
    const int* __restrict__ ei,
    const float* __restrict__ Wl, const float* __restrict__ Wr,
    const float* __restrict__ W1, const float* __restrict__ W2,
    const float* __restrict__ W3, const float* __restrict__ W4,
    unsigned short* __restrict__ xa,
    unsigned short* __restrict__ Wc_, unsigned short* __restrict__ W1_,
    unsigned short* __restrict__ W2_, unsigned short* __restrict__ W3_,
    unsigned short* __restrict__ W4_, int* __restrict__ cnt) {
  __shared__ int h[NBUK];
  int b = blockIdx.x, t = threadIdx.x;
  if (b < 592) {
    int idx = b * 256 + t;
    if (idx < 49152) {
      int k = idx % 192, m = idx / 192;
      Wc_[(size_t)m * 384 + k] = f2bf(Wl[(size_t)k * 256 + m]);
    } else if (idx < 98304) {
      int local = idx - 49152;
      int k = local % 192, m = local / 192;
      Wc_[(size_t)m * 384 + 192 + k] = f2bf(Wr[(size_t)k * 256 + m]);
    } else if (idx < 131072) {
      int local = idx - 98304;
      int k = local % 256, m = local / 256;
      W1_[(size_t)m * 256 + k] = f2bf(W1[(size_t)k * 128 + m]);
    } else if (idx < 139264) {
      int local = idx - 131072;
      int k = local % 128, m = local / 128;
      W2_[(size_t)m * 128 + k] = f2bf(W2[(size_t)k * 64 + m]);
    } else if (idx < 143360) {
      int local = idx - 139264;
      int k = local % 64, m = local / 64;
      W3_[(size_t)m * 64 + k] = f2bf(W3[(size_t)k * 64 + m]);
    } else if (idx < 151552) {
      int local = idx - 143360;
      int k = local % 64, m = local / 64;
      W4_[(size_t)m * 64 + k] = f2bf(W4[(size_t)k * 128 + m]);
    }
  } else if (b < 592 + XCONV_B) {
    int i = (b - 592) * 256 + t;
    if (i < N_NODES * 24) {
      int n = i / 24, s = i % 24;
      float4 va, vb;
      if (s < 16) {
        va = ((const float4*)nf)[(size_t)n * 32 + s * 2];
        vb = ((const float4*)nf)[(size_t)n * 32 + s * 2 + 1];
      } else {
        int u = s - 16;
        va = ((const float4*)noise)[(size_t)n * 16 + u * 2];
        vb = ((const float4*)noise)[(size_t)n * 16 + u * 2 + 1];
      }
      unsigned p0 = (unsigned)f2bf(va.x) | ((unsigned)f2bf(va.y) << 16);
      unsigned p1 = (unsigned)f2bf(va.z) | ((unsigned)f2bf(va.w) << 16);
      unsigned p2 = (unsigned)f2bf(vb.x) | ((unsigned)f2bf(vb.y) << 16);
      unsigned p3 = (unsigned)f2bf(vb.z) | ((unsigned)f2bf(vb.w) << 16);
      *(uint4*)&xa[(size_t)n * 384 + 192 + s * 8] = make_uint4(p0, p1, p2, p3);
    }
  } else {
    int c = b - (592 + XCONV_B);
    for (int i = t; i < NBUK; i += 256) h[i] = 0;
    __syncthreads();
    int e0 = c * CE;
    for (int e = e0 + t; e < e0 + CE; e += 256)
      atomicAdd(&h[ei[E_EDGES + e] >> 7], 1);
    __syncthreads();
    for (int i = t; i < NBUK; i += 256) cnt[i * NCHK + c] = h[i];
  }
}

// ---------------------------------------------------------------------------
// Scan chain.
// ---------------------------------------------------------------------------
template <int LEN>
__global__ __launch_bounds__(256) void block_sum_kernel(
    const int* __restrict__ in, int* __restrict__ bsum) {
  __shared__ int sh[256];
  int i = blockIdx.x * 256 + threadIdx.x;
  sh[threadIdx.x] = (i < LEN) ? in[i] : 0;
  __syncthreads();
  for (int s = 128; s > 0; s >>= 1) {
    if (threadIdx.x < s) sh[threadIdx.x] += sh[threadIdx.x + s];
    __syncthreads();
  }
  if (threadIdx.x == 0) bsum[blockIdx.x] = sh[0];
}

__global__ __launch_bounds__(256) void scan_bsum_kernel(int* __restrict__ bsum) {
  __shared__ int sh[256];
  int t = threadIdx.x;
  sh[t] = (t < NB) ? bsum[t] : 0;
  __syncthreads();
  for (int off = 1; off < 256; off <<= 1) {
    int v = (t >= off) ? sh[t - off] : 0;
    __syncthreads();
    sh[t] += v;
    __syncthreads();
  }
  if (t < NB) bsum[t] = (t == 0) ? 0 : sh[t - 1];
}

template <int LEN>
__global__ __launch_bounds__(256) void scan_chunk_kernel(
    const int* __restrict__ in, const int* __restrict__ bsum,
    int* __restrict__ out) {
  __shared__ int sh[256];
  int t = threadIdx.x;
  int i = blockIdx.x * 256 + t;
  int v = (i < LEN) ? in[i] : 0;
  sh[t] = v;
  __syncthreads();
  for (int off = 1; off < 256; off <<= 1) {
    int u = (t >= off) ? sh[t - off] : 0;
    __syncthreads();
    sh[t] += u;
    __syncthreads();
  }
  if (i < LEN) out[i] = bsum[blockIdx.x] + sh[t] - v;
}

__global__ __launch_bounds__(256) void scatter_kernel(
    const int* __restrict__ ei, const int* __restrict__ ebase,
    unsigned* __restrict__ ebuf) {
  __shared__ int cur[NBUK];
  int c = blockIdx.x, t = threadIdx.x;
  for (int i = t; i < NBUK; i += 256) cur[i] = ebase[i * NCHK + c];
  __syncthreads();
  int e0 = c * CE;
  for (int e = e0 + t; e < e0 + CE; e += 256) {
    int s = ei[e], d = ei[E_EDGES + e];
    int p = atomicAdd(&cur[d >> 7], 1);
    ebuf[p] = ((unsigned)(d & 127) << 16) | (unsigned)s;
  }
}

__global__ __launch_bounds__(256) void sortb_kernel(
    const unsigned* __restrict__ ebuf, const int* __restrict__ ebase,
    int* __restrict__ csr, int* __restrict__ deg, int* __restrict__ cursor) {
  __shared__ int h[128], sc[128], curn[128];
  int b = blockIdx.x, t = threadIdx.x;
  int beg = ebase[b * NCHK];
  int endb = (b == NBUK - 1) ? E_EDGES : ebase[(b + 1) * NCHK];
  if (t < 128) h[t] = 0;
  __syncthreads();
  for (int i = beg + t; i < endb; i += 256) atomicAdd(&h[ebuf[i] >> 16], 1);
  __syncthreads();
  if (t < 128) sc[t] = h[t];
  __syncthreads();
  for (int off = 1; off < 128; off <<= 1) {
    int v = (t >= off && t < 128) ? sc[t - off] : 0;
    __syncthreads();
    if (t < 128) sc[t] += v;
    __syncthreads();
  }
  if (t < 128) {
    curn[t] = sc[t] - h[t];
    int n = b * 128 + t;
    if (n < N_NODES) {
      deg[n] = h[t];
      cursor[n] = beg + sc[t];
    }
  }
  __syncthreads();
  for (int i = beg + t; i < endb; i += 256) {
    unsigned u = ebuf[i];
    int p = atomicAdd(&curn[u >> 16], 1);
    csr[beg + p] = (int)(u & 0xFFFFu) * 768 + 384;  // byte offset of x-part
  }
}

// ---------------------------------------------------------------------------
// Gather (request-rate bound at ~6.3 TB/s effective).
// ---------------------------------------------------------------------------
__global__ __launch_bounds__(256) void gather_kernel(
    const int* __restrict__ csr, const int* __restrict__ cursor,
    const int* __restrict__ deg, unsigned short* __restrict__ xa) {
  int wid = (blockIdx.x * blockDim.x + threadIdx.x) >> 6;
  int lane = threadIdx.x & 63;
  if (wid >= N_NODES) return;
  int d = deg[wid];
  int end = cursor[wid];
  int start = end - d;
  const bool act = lane < 48;
  const char* base = (const char*)xa + (size_t)(lane * 8);

  float a0 = 0.f, a1 = 0.f, a2 = 0.f, a3 = 0.f;
  float b0 = 0.f, b1 = 0.f, b2 = 0.f, b3 = 0.f;
  int j = start;
  for (; j + 7 < end; j += 8) {
    int o0 = csr[j],     o1 = csr[j + 1], o2 = csr[j + 2], o3 = csr[j + 3];
    int o4 = csr[j + 4], o5 = csr[j + 5], o6 = csr[j + 6], o7 = csr[j + 7];
    if (act) {
      uint2 v0 = *(const uint2*)(base + o0);
      uint2 v1 = *(const uint2*)(base + o1);
      uint2 v2 = *(const uint2*)(base + o2);
      uint2 v3 = *(const uint2*)(base + o3);
      uint2 v4 = *(const uint2*)(base + o4);
      uint2 v5 = *(const uint2*)(base + o5);
      uint2 v6 = *(const uint2*)(base + o6);
      uint2 v7 = *(const uint2*)(base + o7);
      a0 += bflo32(v0.x) + bflo32(v2.x) + bflo32(v4.x) + bflo32(v6.x);
      a1 += bfhi32(v0.x) + bfhi32(v2.x) + bfhi32(v4.x) + bfhi32(v6.x);
      a2 += bflo32(v0.y) + bflo32(v2.y) + bflo32(v4.y) + bflo32(v6.y);
      a3 += bfhi32(v0.y) + bfhi32(v2.y) + bfhi32(v4.y) + bfhi32(v6.y);
      b0 += bflo32(v1.x) + bflo32(v3.x) + bflo32(v5.x) + bflo32(v7.x);
      b1 += bfhi32(v1.x) + bfhi32(v3.x) + bfhi32(v5.x) + bfhi32(v7.x);
      b2 += bflo32(v1.y) + bflo32(v3.y) + bflo32(v5.y) + bflo32(v7.y);
      b3 += bfhi32(v1.y) + bfhi32(v3.y) + bfhi32(v5.y) + bfhi32(v7.y);
    }
  }
  for (; j < end; ++j) {
    int o = csr[j];
    if (act) {
      uint2 v = *(const uint2*)(base + o);
      a0 += bflo32(v.x); a1 += bfhi32(v.x);
      a2 += bflo32(v.y); a3 += bfhi32(v.y);
    }
  }
  if (act) {
    float inv = 1.0f / fmaxf((float)d, 1.0f);
    float m0 = (a0 + b0) * inv, m1 = (a1 + b1) * inv;
    float m2 = (a2 + b2) * inv, m3 = (a3 + b3) * inv;
    unsigned r0 = (unsigned)f2bf(m0) | ((unsigned)f2bf(m1) << 16);
    unsigned r1 = (unsigned)f2bf(m2) | ((unsigned)f2bf(m3) << 16);
    *(uint2*)&xa[(size_t)wid * 384 + (size_t)lane * 4] = make_uint2(r0, r1);
  }
}

// ---------------------------------------------------------------------------
// Plain bf16 MFMA GEMM (round-8 proven). PAIR=true: 1-D grid of 2*GRB blocks
// remapped so the two col-half blocks of one row stripe get linear IDs 8
// apart (= same XCD under round-robin) -> A stripe shared in one L2.
// ---------------------------------------------------------------------------
template <int KBASE, int ALD, int OUTLD, int OUT_MODE, bool PAIR>
__global__ __launch_bounds__(256) void gemm_plain(
    const unsigned short* __restrict__ Ab, const unsigned short* __restrict__ Bb,
    const float* __restrict__ bias, const float* __restrict__ gamma,
    const float* __restrict__ beta, const float* __restrict__ bmean,
    const float* __restrict__ bvar, unsigned short* __restrict__ outp) {
  constexpr int BM = 128, BK = 64;
  constexpr int NITER = KBASE / BK;
  constexpr int GRB = NPAD / 128;  // 391

  __shared__ unsigned short lds[16384];  // 32 KB
  unsigned short* sA = lds;
  unsigned short* sB = lds + 8192;

  const int tid = threadIdx.x;
  const int wid = tid >> 6;
  const int lane = tid & 63;

  int rb, cb;
  if (PAIR) {
    int bid = blockIdx.x;
    int g = bid >> 4, r = bid & 15;
    int rem = GRB - g * 8; if (rem > 8) rem = 8;
    cb = (r >= rem) ? 1 : 0;
    rb = g * 8 + (cb ? r - rem : r);
  } else {
    rb = blockIdx.x; cb = 0;
  }
  const int rowbase = rb * BM;
  const int colbase = cb * 128;
  const int wr = wid >> 1, wc = wid & 1;

  f32x4 acc[4][4];
#pragma unroll
  for (int i = 0; i < 4; ++i)
#pragma unroll
    for (int j = 0; j < 4; ++j) acc[i][j] = (f32x4)0.f;

  for (int kt = 0; kt < NITER; ++kt) {
    const int kb = kt * BK;
    __syncthreads();
#pragma unroll
    for (int j = 0; j < 4; ++j) {
      int o = j * 4 + wid;
      int row = o * 8 + (lane >> 3);
      int slog = (lane & 7) ^ (lane >> 3);
      const char* src = (const char*)Bb +
          ((size_t)(colbase + row) * KBASE + kb) * 2 + (size_t)slog * 16;
      gload16(src, sB + o * 512);
    }
#pragma unroll
    for (int j = 0; j < 4; ++j) {
      int o = j * 4 + wid;
      int row = o * 8 + (lane >> 3);
      int slog = (lane & 7) ^ (lane >> 3);
      const char* src = (const char*)Ab +
          ((size_t)(rowbase + row) * ALD + kb) * 2 + (size_t)slog * 16;
      gload16(src, sA + o * 512);
    }
    __syncthreads();

#pragma unroll
    for (int kk = 0; kk < 2; ++kk) {
      short8v a[4], b[4];
#pragma unroll
      for (int fi = 0; fi < 4; ++fi) {
        int rt = wr * 64 + fi * 16 + (lane & 15);
        int sl = (kk * 4 + (lane >> 4)) ^ (rt & 7);
        a[fi] = *(const short8v*)&sA[rt * 64 + sl * 8];
      }
#pragma unroll
      for (int fj = 0; fj < 4; ++fj) {
        int ct = wc * 64 + fj * 16 + (lane & 15);
        int sl = (kk * 4 + (lane >> 4)) ^ (ct & 7);
        b[fj] = *(const short8v*)&sB[ct * 64 + sl * 8];
      }
#pragma unroll
      for (int fi = 0; fi < 4; ++fi)
#pragma unroll
        for (int fj = 0; fj < 4; ++fj)
          acc[fi][fj] = __builtin_amdgcn_mfma_f32_16x16x32_bf16(
              a[fi], b[fj], acc[fi][fj], 0, 0, 0);
    }
  }

  __syncthreads();
#pragma unroll
  for (int fj = 0; fj < 4; ++fj) {
    int gcl = wc * 64 + fj * 16 + (lane & 15);
    int gc = colbase + gcl;
    float sc, sh;
    if (OUT_MODE == 0) {
      float s = gamma[gc] * rsqrtf(bvar[gc] + BN_EPS);
      sc = s; sh = bias[gc] * s + beta[gc] - bmean[gc] * s;
    } else {
      sc = 1.f; sh = bias[gc];
    }
#pragma unroll
    for (int fi = 0; fi < 4; ++fi)
#pragma unroll
      for (int r = 0; r < 4; ++r) {
        int rt = wr * 64 + fi * 16 + ((lane >> 4) << 2) + r;
        float v = acc[fi][fj][r] * sc + sh;
        v = (v >= 0.f) ? v : SLOPE * v;
        lds[rt * 128 + gcl] = f2bf(v);
      }
  }
  __syncthreads();
#pragma unroll
  for (int i0 = 0; i0 < 8; ++i0) {
    int i = tid + i0 * 256;
    int row = i >> 4, u4 = i & 15;
    ((uint4*)(outp + (size_t)(rowbase + row) * OUTLD + colbase))[u4] =
        ((const uint4*)lds)[i];
  }
}

// ---------------------------------------------------------------------------
// Fused fc2+fc3+fc4 (round-8 proven).
// ---------------------------------------------------------------------------
__global__ __launch_bounds__(256) void fc234_kernel(
    const unsigned short* __restrict__ h1p,
    const unsigned short* __restrict__ W2_, const unsigned short* __restrict__ W3_,
    const unsigned short* __restrict__ W4_,
    const float* __restrict__ b2, const float* __restrict__ b3,
    const float* __restrict__ b4, float* __restrict__ outp) {
  __shared__ unsigned short lds[32768];
  unsigned short* SA  = lds;
  unsigned short* SB  = lds + 16384;
  unsigned short* SH2 = lds + 24576;

  const int tid = threadIdx.x;
  const int wid = tid >> 6;
  const int lane = tid & 63;
  const int rowbase = blockIdx.x * 128;
  const int wr = wid >> 1, wc = wid & 1;

#pragma unroll
  for (int j = 0; j < 8; ++j) {
    int o = j * 4 + wid;
    int rloc = o * 4 + (lane >> 4);
    int slog = (lane & 15) ^ ((rloc & 7) << 1);
    const char* src = (const char*)h1p +
        ((size_t)(rowbase + rloc) * 128) * 2 + (size_t)slog * 16;
    gload16(src, SA + o * 512);
  }
#pragma unroll
  for (int j = 0; j < 4; ++j) {
    int o = j * 4 + wid;
    int rloc = o * 4 + (lane >> 4);
    int slog = (lane & 15) ^ ((rloc & 7) << 1);
    const char* src = (const char*)W2_ +
        ((size_t)rloc * 128) * 2 + (size_t)slog * 16;
    gload16(src, SB + o * 512);
  }
  __syncthreads();

  f32x4 acc2[4][2];
#pragma unroll
  for (int i = 0; i < 4; ++i) { acc2[i][0] = (f32x4)0.f; acc2[i][1] = (f32x4)0.f; }
#pragma unroll
  for (int kk = 0; kk < 4; ++kk) {
    short8v a[4], b[2];
#pragma unroll
    for (int fi = 0; fi < 4; ++fi) {
      int rt = wr * 64 + fi * 16 + (lane & 15);
      int ph = (kk * 4 + (lane >> 4)) ^ ((rt & 7) << 1);
      a[fi] = *(const short8v*)&SA[rt * 128 + ph * 8];
    }
#pragma unroll
    for (int fj = 0; fj < 2; ++fj) {
      int ct = wc * 32 + fj * 16 + (lane & 15);
      int ph = (kk * 4 + (lane >> 4)) ^ ((ct & 7) << 1);
      b[fj] = *(const short8v*)&SB[ct * 128 + ph * 8];
    }
#pragma unroll
    for (int fi = 0; fi < 4; ++fi)
#pragma unroll
      for (int fj = 0; fj < 2; ++fj)
        acc2[fi][fj] = __builtin_amdgcn_mfma_f32_16x16x32_bf16(
            a[fi], b[fj], acc2[fi][fj], 0, 0, 0);
  }
  __syncthreads();

#pragma unroll
  for (int fj = 0; fj < 2; ++fj) {
    int gc = wc * 32 + fj * 16 + (lane & 15);
    float bb = b2[gc];
#pragma unroll
    for (int fi = 0; fi < 4; ++fi)
#pragma unroll
      for (int r = 0; r < 4; ++r) {
        int rt = wr * 64 + fi * 16 + ((lane >> 4) << 2) + r;
        float v = acc2[fi][fj][r] + bb;
        v = (v >= 0.f) ? v : SLOPE * v;
        SH2[rt * 64 + ((gc >> 3) ^ (rt & 7)) * 8 + (gc & 7)] = f2bf(v);
      }
  }
#pragma unroll
  for (int j = 0; j < 2; ++j) {
    int o = j * 4 + wid;
    int rloc = o * 8 + (lane >> 3);
    int slog = (lane & 7) ^ (lane >> 3);
    const char* src = (const char*)W3_ +
        ((size_t)rloc * 64) * 2 + (size_t)slog * 16;
    gload16(src, SB + o * 512);
  }
  __syncthreads();

  f32x4 acc3[4][2];
#pragma unroll
  for (int i = 0; i < 4; ++i) { acc3[i][0] = (f32x4)0.f; acc3[i][1] = (f32x4)0.f; }
#pragma unroll
  for (int kk = 0; kk < 2; ++kk) {
    short8v a[4], b[2];
#pragma unroll
    for (int fi = 0; fi < 4; ++fi) {
      int rt = wr * 64 + fi * 16 + (lane & 15);
      int ph = (kk * 4 + (lane >> 4)) ^ (rt & 7);
      a[fi] = *(const short8v*)&SH2[rt * 64 + ph * 8];
    }
#pragma unroll
    for (int fj = 0; fj < 2; ++fj) {
      int ct = wc * 32 + fj * 16 + (lane & 15);
      int ph = (kk * 4 + (lane >> 4)) ^ (ct & 7);
      b[fj] = *(const short8v*)&SB[ct * 64 + ph * 8];
    }
#pragma unroll
    for (int fi = 0; fi < 4; ++fi)
#pragma unroll
      for (int fj = 0; fj < 2; ++fj)
        acc3[fi][fj] = __builtin_amdgcn_mfma_f32_16x16x32_bf16(
            a[fi], b[fj], acc3[fi][fj], 0, 0, 0);
  }
  __syncthreads();

  unsigned short* SH3 = SA;
#pragma unroll
  for (int fj = 0; fj < 2; ++fj) {
    int gc = wc * 32 + fj * 16 + (lane & 15);
    float bb = b3[gc];
#pragma unroll
    for (int fi = 0; fi < 4; ++fi)
#pragma unroll
      for (int r = 0; r < 4; ++r) {
        int rt = wr * 64 + fi * 16 + ((lane >> 4) << 2) + r;
        float v = acc3[fi][fj][r] + bb;
        v = (v >= 0.f) ? v : SLOPE * v;
        SH3[rt * 64 + ((gc >> 3) ^ (rt & 7)) * 8 + (gc & 7)] = f2bf(v);
      }
  }
#pragma unroll
  for (int j = 0; j < 4; ++j) {
    int o = j * 4 + wid;
    int rloc = o * 8 + (lane >> 3);
    int slog = (lane & 7) ^ (lane >> 3);
    const char* src = (const char*)W4_ +
        ((size_t)rloc * 64) * 2 + (size_t)slog * 16;
    gload16(src, SB + o * 512);
  }
  __syncthreads();

  f32x4 acc4[4][4];
#pragma unroll
  for (int i = 0; i < 4; ++i)
#pragma unroll
    for (int j = 0; j < 4; ++j) acc4[i][j] = (f32x4)0.f;
#pragma unroll
  for (int kk = 0; kk < 2; ++kk) {
    short8v a[4], b[4];
#pragma unroll
    for (int fi = 0; fi < 4; ++fi) {
      int rt = wr * 64 + fi * 16 + (lane & 15);
      int ph = (kk * 4 + (lane >> 4)) ^ (rt & 7);
      a[fi] = *(const short8v*)&SH3[rt * 64 + ph * 8];
    }
#pragma unroll
    for (int fj = 0; fj < 4; ++fj) {
      int ct = wc * 64 + fj * 16 + (lane & 15);
      int ph = (kk * 4 + (lane >> 4)) ^ (ct & 7);
      b[fj] = *(const short8v*)&SB[ct * 64 + ph * 8];
    }
#pragma unroll
    for (int fi = 0; fi < 4; ++fi)
#pragma unroll
      for (int fj = 0; fj < 4; ++fj)
        acc4[fi][fj] = __builtin_amdgcn_mfma_f32_16x16x32_bf16(
            a[fi], b[fj], acc4[fi][fj], 0, 0, 0);
  }

  const int crow0 = rowbase + wr * 64;
#pragma unroll
  for (int fj = 0; fj < 4; ++fj) {
    int gc = wc * 64 + fj * 16 + (lane & 15);
    float bb = b4[gc];
#pragma unroll
    for (int fi = 0; fi < 4; ++fi)
#pragma unroll
      for (int r = 0; r < 4; ++r) {
        int gr = crow0 + fi * 16 + ((lane >> 4) << 2) + r;
        if (gr < N_NODES) {
          float v = acc4[fi][fj][r] + bb;
          v = (v >= 0.f) ? v : SLOPE * v;
          outp[(size_t)gr * FEAT + gc] = v;
        }
      }
  }
}

extern "C" void kernel_launch(void* const* d_in, const int* in_sizes, int n_in,
                              void* d_out, int out_size, void* d_ws, size_t ws_size,
                              hipStream_t stream) {
  const float* nf    = (const float*)d_in[0];
  const float* noise = (const float*)d_in[1];
  const int*   ei    = (const int*)d_in[2];
  const float* Wl    = (const float*)d_in[4];
  const float* bl    = (const float*)d_in[5];
  const float* Wr    = (const float*)d_in[6];
  const float* gam   = (const float*)d_in[7];
  const float* bet   = (const float*)d_in[8];
  const float* bmean = (const float*)d_in[9];
  const float* bvar  = (const float*)d_in[10];
  const float* fc1w  = (const float*)d_in[11];
  const float* fc1b  = (const float*)d_in[12];
  const float* fc2w  = (const float*)d_in[13];
  const float* fc2b  = (const float*)d_in[14];
  const float* fc3w  = (const float*)d_in[15];
  const float* fc3b  = (const float*)d_in[16];
  const float* fc4w  = (const float*)d_in[17];
  const float* fc4b  = (const float*)d_in[18];
  float* outp = (float*)d_out;

  // ---- workspace (ushort units unless noted) ----
  unsigned short* xa  = (unsigned short*)d_ws;             // [NPAD][384]: [agg|x]
  unsigned short* hp  = xa + (size_t)NPAD * 384;           // [NPAD][256]
  unsigned short* Wc_ = hp + (size_t)NPAD * 256;           // 256*384
  unsigned short* W1_ = Wc_ + 256 * 384;                   // 128*256
  unsigned short* W2_ = W1_ + 128 * 256;                   // 64*128
  unsigned short* W3_ = W2_ + 64 * 128;                    // 64*64
  unsigned short* W4_ = W3_ + 64 * 64;                     // 128*64
  int* deg    = (int*)(W4_ + 128 * 64);                    // N
  int* cursor = deg + N_NODES;                             // N
  int* bsum   = cursor + N_NODES;                          // 256
  int* cnt    = bsum + 256;                                // NBUK*NCHK
  int* ebase  = cnt + NBUK * NCHK;                         // NBUK*NCHK
  unsigned short* h1p = xa;                                // [NPAD][128] (xa dead after combine)
  int*      csr  = (int*)d_out;                            // E ints (scratch)
  unsigned* ebuf = (unsigned*)d_out + E_EDGES;             // E uints (scratch)

  // --- prep: wconv + xconv + hist in one launch ---
  prep_kernel<<<592 + XCONV_B + NCHK, 256, 0, stream>>>(
      nf, noise, ei, Wl, Wr, fc1w, fc2w, fc3w, fc4w,
      xa, Wc_, W1_, W2_, W3_, W4_, cnt);

  // --- scan + scatter + per-bucket sort ---
  block_sum_kernel<NBUK * NCHK><<<NB, 256, 0, stream>>>(cnt, bsum);
  scan_bsum_kernel<<<1, 256, 0, stream>>>(bsum);
  scan_chunk_kernel<NBUK * NCHK><<<NB, 256, 0, stream>>>(cnt, bsum, ebase);
  scatter_kernel<<<NCHK, 256, 0, stream>>>(ei, ebase, ebuf);
  sortb_kernel<<<NBUK, 256, 0, stream>>>(ebuf, ebase, csr, deg, cursor);

  // --- aggregate ---
  gather_kernel<<<(N_NODES + 3) / 4, 256, 0, stream>>>(csr, cursor, deg, xa);

  const int RB = NPAD / 128;  // 391

  // --- combine: K=384, 2*RB paired blocks, out 256 cols + BN+lrelu ---
  gemm_plain<384, 384, 256, 0, true><<<2 * RB, 256, 0, stream>>>(
      xa, Wc_, bl, gam, bet, bmean, bvar, hp);
  // --- fc1: K=256, out 128 cols + bias+lrelu ---
  gemm_plain<256, 256, 128, 1, false><<<RB, 256, 0, stream>>>(
      hp, W1_, fc1b, nullptr, nullptr, nullptr, nullptr, h1p);
  // --- fused fc2+fc3+fc4 -> f32 out ---
  fc234_kernel<<<RB, 256, 0, stream>>>(h1p, W2_, W3_, W4_,
                                       fc2b, fc3b, fc4b, outp);
}